// Round 2
// baseline (1737.704 us; speedup 1.0000x reference)
//
#include <hip/hip_runtime.h>

// convPbc as implicit GEMM, round 4: counted-vmcnt pipeline (T3+T4) + setprio (T5)
// + XCD-chunked block swizzle (T1).
//   Main loop: raw s_barrier with s_waitcnt vmcnt(10) BEFORE it (never vmcnt(0) in
//   steady state). Per phase (one 32-wide k-step): issue B-DMA for step i+3 (2x
//   global_load_lds dwordx4, 4 rotating 8KB LDS buffers) and A-gather for step i+2
//   (8x dwordx2 into 4 rotating named register sets), then ds_read B frags + 16 MFMA.
//   Both operands get 2-phase latency cover across barriers. Tail peeled with
//   decreasing waits [10,10,8,0].

#define BM 128
#define BN 128

typedef __attribute__((ext_vector_type(8))) short short8;
typedef __attribute__((ext_vector_type(4))) float f32x4;

struct __attribute__((packed)) u16x4 { unsigned short a, b, c, d; };  // 8B, 2B-align

__device__ __forceinline__ unsigned short f2bf(float f) {
    union { float f; unsigned u; } v; v.f = f;
    unsigned r = v.u + 0x7FFF + ((v.u >> 16) & 1);  // RNE
    return (unsigned short)(r >> 16);
}

__device__ __forceinline__ void async_b128(const void* g, void* l) {
    __builtin_amdgcn_global_load_lds(
        (const __attribute__((address_space(1))) void*)g,
        (__attribute__((address_space(3))) void*)l, 16, 0, 0);
}

// ---------------- pre-pass kernels ----------------
// flat-indexed: every thread handles one 16B chunk; chunk id -> (bc, t) via const-div.
__global__ __launch_bounds__(256) void build_pad_vec2(const float* __restrict__ x,
                                                      unsigned short* __restrict__ xp) {
    const int idx = blockIdx.x * 256 + threadIdx.x;   // 0 .. 32768*154-1
    const int bc  = idx / 154;                        // compiler magic-div
    const int t   = idx - bc * 154;
    if (bc >= 32768) return;
    const float* xb = x + (long)bc * 1024;
    union { unsigned short h[8]; short8 v; } u;
    if (t < 128) {                                    // pure copy region v<1024
        const float4 f0 = *(const float4*)(xb + t * 8);
        const float4 f1 = *(const float4*)(xb + t * 8 + 4);
        u.h[0] = f2bf(f0.x); u.h[1] = f2bf(f0.y); u.h[2] = f2bf(f0.z); u.h[3] = f2bf(f0.w);
        u.h[4] = f2bf(f1.x); u.h[5] = f2bf(f1.y); u.h[6] = f2bf(f1.z); u.h[7] = f2bf(f1.w);
    } else {                                          // pad region 1024..1231
        #pragma unroll
        for (int e = 0; e < 8; ++e) {
            const int v = t * 8 + e;
            const int p = (v * 7490) >> 18;           // exact v/35 for v<43690
            const int q = v - p * 35;
            float val = 0.0f;
            if (p >= 32 && q >= 32) val = xb[((p - 32) << 5) + (q - 32)];
            u.h[e] = f2bf(val);
        }
    }
    *(short8*)(xp + (long)bc * 1232 + t * 8) = u.v;
}

// scalar fallback (stride 1225)
__global__ __launch_bounds__(256) void build_pad_s(const float* __restrict__ x,
                                                   unsigned short* __restrict__ xp) {
    const int v = blockIdx.x * 256 + threadIdx.x;
    const int bc = blockIdx.y;
    if (v >= 1225) return;
    const int p = (v * 7490) >> 18;
    const int q = v - p * 35;
    const float* xb = x + (long)bc * 1024;
    float val = (v < 1024) ? xb[v] : 0.0f;
    if (p >= 32 && q >= 32) val += xb[((p - 32) << 5) + (q - 32)];
    xp[(long)bc * 1225 + v] = f2bf(val);
}

__global__ __launch_bounds__(256) void cvt_w(const float* __restrict__ W,
                                             unsigned short* __restrict__ Wb) {
    const int i = (blockIdx.x * 256 + threadIdx.x) * 8;   // 2M elems / 8
    const float4 f0 = *(const float4*)(W + i);
    const float4 f1 = *(const float4*)(W + i + 4);
    union { unsigned short h[8]; short8 v; } u;
    u.h[0] = f2bf(f0.x); u.h[1] = f2bf(f0.y); u.h[2] = f2bf(f0.z); u.h[3] = f2bf(f0.w);
    u.h[4] = f2bf(f1.x); u.h[5] = f2bf(f1.y); u.h[6] = f2bf(f1.z); u.h[7] = f2bf(f1.w);
    *(short8*)(Wb + i) = u.v;
}

// ---------------- main kernel (counted-vmcnt pipeline) ----------------
__global__ __launch_bounds__(256, 3) void convpbc_mfma4(
    const unsigned short* __restrict__ xpad,  // (128,256,cstride) bf16
    const unsigned short* __restrict__ Wb,    // (512,4096) bf16
    const float* __restrict__ bias,
    float* __restrict__ y,
    const int cstride)
{
    // 4 double... quad-buffered B tiles, 8KB each (128 rows x 32 k, XOR-swizzled segs)
    __shared__ __attribute__((aligned(16))) unsigned short Blds[4 * 4096];  // 32 KB

    const int tid = threadIdx.x;
    // T1: XCD-chunked swizzle. grid=4096, 8 XCDs, 4096%8==0 -> bijective.
    const int bid = (blockIdx.x & 7) * 512 + (blockIdx.x >> 3);
    const int nt = bid & 3;
    const int mt = bid >> 2;
    const int batch = mt >> 3;
    const int s0 = (mt & 7) * BM;
    const int i0 = (mt & 7) * 4;

    const int lane = tid & 63;
    const int w    = tid >> 6;
    const int wm   = (w >> 1) * 64;
    const int wn   = (w & 1) * 64;
    const int lr   = lane & 15;
    const int quad = lane >> 4;

    // ---- A direct-load setup (helical pad: each frag = 2 runs of 4 consecutive) ----
    const int fi0 = (quad & 1) * 2;
    const unsigned short* ab = xpad + (long)(batch * 256 + (quad >> 1)) * cstride;
    int aoff[4];
    #pragma unroll
    for (int mi = 0; mi < 4; ++mi) {
        const int i_mi = i0 + (wm >> 5) + (mi >> 1) + fi0;
        const int j_mi = (mi & 1) * 16 + lr;
        aoff[mi] = i_mi * 35 + j_mi;
    }
    const int csStep = 2 * cstride;   // one k-step = 2 channels

    // ---- B staging setup (global_load_lds, XOR-swizzled k-segments) ----
    const int brow0 = w * 32 + (lane >> 2);
    const int brow1 = brow0 + 16;
    const int bseg  = lane & 3;
    const unsigned short* bg0 =
        Wb + (long)(nt * BN + brow0) * 4096 + (bseg ^ ((brow0 >> 1) & 3)) * 8;
    const unsigned short* bg1 =
        Wb + (long)(nt * BN + brow1) * 4096 + (bseg ^ ((brow1 >> 1) & 3)) * 8;
    unsigned short* const blA = &Blds[(w * 32) * 32];        // wave-uniform DMA bases
    unsigned short* const blB = blA + 512;

    int bfaddr[4];
    #pragma unroll
    for (int ni = 0; ni < 4; ++ni) {
        const int row = wn + ni * 16 + lr;
        bfaddr[ni] = row * 32 + (quad ^ ((row >> 1) & 3)) * 8;
    }

    f32x4 acc[4][4] = {};
    short8 af0[4], af1[4], af2[4], af3[4];

    const unsigned short* bg0i = bg0;
    const unsigned short* bg1i = bg1;
    const unsigned short* abi  = ab;

    // Per-phase vmem group = [B-DMA x2, A-loads x8] = 10 ops.
    #define ISSUE_B(BUF, OFF)                                                  \
        async_b128(bg0i + (OFF) * 32, blA + (BUF) * 4096);                     \
        async_b128(bg1i + (OFF) * 32, blB + (BUF) * 4096);
    #define ISSUE_A(SET, OFF)                                                  \
        {                                                                      \
            const unsigned short* ap_ = abi + (OFF) * csStep;                  \
            _Pragma("unroll")                                                  \
            for (int mi = 0; mi < 4; ++mi) {                                   \
                union { unsigned short h[8]; short8 f; } u_;                   \
                *(u16x4*)&u_.h[0] = *(const u16x4*)(ap_ + aoff[mi]);           \
                *(u16x4*)&u_.h[4] = *(const u16x4*)(ap_ + aoff[mi] + 35);      \
                SET[mi] = u_.f;                                                \
            }                                                                  \
        }
    // wait-for-own-DMA BEFORE the barrier (cross-wave LDS visibility), counted N.
    #define BARRIER_WAIT(N)                                                    \
        asm volatile("s_waitcnt vmcnt(" #N ")" ::: "memory");                  \
        __builtin_amdgcn_s_barrier();                                          \
        __builtin_amdgcn_sched_barrier(0);
    #define COMPUTE_STEP(SET, BUF)                                             \
        {                                                                      \
            short8 bf[4];                                                      \
            _Pragma("unroll")                                                  \
            for (int ni = 0; ni < 4; ++ni)                                     \
                bf[ni] = *(const short8*)&Blds[(BUF) * 4096 + bfaddr[ni]];     \
            __builtin_amdgcn_s_setprio(1);                                     \
            _Pragma("unroll")                                                  \
            for (int mi = 0; mi < 4; ++mi)                                     \
                _Pragma("unroll")                                              \
                for (int ni = 0; ni < 4; ++ni)                                 \
                    acc[mi][ni] = __builtin_amdgcn_mfma_f32_16x16x32_bf16(     \
                        SET[mi], bf[ni], acc[mi][ni], 0, 0, 0);                \
            __builtin_amdgcn_s_setprio(0);                                     \
        }

    // prologue: B(0),B(1),A(0),B(2),A(1)  -> 22 ops in flight
    ISSUE_B(0, 0)
    ISSUE_B(1, 1)
    ISSUE_A(af0, 0)
    ISSUE_B(2, 2)
    ISSUE_A(af1, 1)

    // main loop: 31 iters x 4 phases = steps 0..123.
    // phase i: vmcnt(10) retires B(i),A(i); issue B(i+3) (buf (i+3)%4), A(i+2)
    // (set (i+2)%4). Entering each phase: 20 outstanding; after wait: 10.
    for (int kb = 0; kb < 31; ++kb) {
        BARRIER_WAIT(10) ISSUE_B(3, 3) ISSUE_A(af2, 2) COMPUTE_STEP(af0, 0)
        BARRIER_WAIT(10) ISSUE_B(0, 4) ISSUE_A(af3, 3) COMPUTE_STEP(af1, 1)
        BARRIER_WAIT(10) ISSUE_B(1, 5) ISSUE_A(af0, 4) COMPUTE_STEP(af2, 2)
        BARRIER_WAIT(10) ISSUE_B(2, 6) ISSUE_A(af1, 5) COMPUTE_STEP(af3, 3)
        bg0i += 128; bg1i += 128; abi += 4 * csStep;
    }
    // peel: steps 124..127 (abi/bgi now at step-124 base)
    BARRIER_WAIT(10) ISSUE_B(3, 3) ISSUE_A(af2, 2) COMPUTE_STEP(af0, 0)   // 124
    BARRIER_WAIT(10) ISSUE_A(af3, 3)               COMPUTE_STEP(af1, 1)   // 125
    BARRIER_WAIT(8)                                COMPUTE_STEP(af2, 2)   // 126
    BARRIER_WAIT(0)                                COMPUTE_STEP(af3, 3)   // 127

    #undef ISSUE_B
    #undef ISSUE_A
    #undef BARRIER_WAIT
    #undef COMPUTE_STEP

    // ---- epilogue: C/D layout col=lane&15, row=quad*4+r ----
    #pragma unroll
    for (int ni = 0; ni < 4; ++ni) {
        const int ngl = nt * BN + wn + ni * 16 + lr;
        const float bv = bias[ngl];
        float* ybase = y + (((long)(batch * 512 + ngl)) << 10) + s0;
        #pragma unroll
        for (int mi = 0; mi < 4; ++mi) {
            const int mbase = wm + mi * 16 + quad * 4;
            #pragma unroll
            for (int r = 0; r < 4; ++r)
                ybase[mbase + r] = acc[mi][ni][r] + bv;
        }
    }
}

// ---------------- legacy fallback (fp32 direct, ws too small) ----------------
#define LDA 40
#define LDB 40
__global__ __launch_bounds__(256) void convpbc_mfma(
    const float* __restrict__ x, const float* __restrict__ W,
    const float* __restrict__ bias, float* __restrict__ y)
{
    __shared__ __attribute__((aligned(16))) unsigned short Alds[BM * LDA];
    __shared__ __attribute__((aligned(16))) unsigned short BldsL[BN * LDB];
    const int tid = threadIdx.x, bid = blockIdx.x;
    const int nt = bid & 3, mt = bid >> 2, batch = mt >> 3;
    const int s0 = (mt & 7) * BM;
    const int lane = tid & 63, w = tid >> 6;
    const int wm = (w >> 1) * 64, wn = (w & 1) * 64;
    const int lr = lane & 15, quad = lane >> 4;
    const int sm = tid >> 1, half = tid & 1;
    const int s = s0 + sm, i0 = s >> 5, j0 = s & 31;
    const float* wrow = W + (long)(nt * BN + sm) * 4096;
    f32x4 acc[4][4] = {};
    for (int k0 = 0; k0 < 4096; k0 += 32) {
        {
            const int c = (k0 >> 4) + half;
            const float* xp = x + (((long)(batch * 256 + c)) << 10);
            __attribute__((aligned(16))) unsigned short tmp[16];
            #pragma unroll
            for (int t = 0; t < 16; ++t) {
                const int p = i0 + (t >> 2), q = j0 + (t & 3);
                const int v = p * 35 + q;
                const bool corner = (p >= 32) & (q >= 32);
                const bool valid = corner | (v < 1024);
                int idx = corner ? (((p - 32) << 5) + (q - 32)) : v;
                idx = valid ? idx : 0;
                float fv = xp[idx];
                fv = valid ? fv : 0.0f;
                tmp[t] = f2bf(fv);
            }
            short8* dst = (short8*)&Alds[sm * LDA + half * 16];
            dst[0] = *(const short8*)&tmp[0];
            dst[1] = *(const short8*)&tmp[8];
        }
        {
            const float4* wv = (const float4*)(wrow + k0 + half * 16);
            __attribute__((aligned(16))) unsigned short tmp[16];
            #pragma unroll
            for (int t4 = 0; t4 < 4; ++t4) {
                const float4 f = wv[t4];
                tmp[t4 * 4 + 0] = f2bf(f.x); tmp[t4 * 4 + 1] = f2bf(f.y);
                tmp[t4 * 4 + 2] = f2bf(f.z); tmp[t4 * 4 + 3] = f2bf(f.w);
            }
            short8* dst = (short8*)&BldsL[sm * LDB + half * 16];
            dst[0] = *(const short8*)&tmp[0];
            dst[1] = *(const short8*)&tmp[8];
        }
        __syncthreads();
        short8 af[4], bf[4];
        #pragma unroll
        for (int mi = 0; mi < 4; ++mi)
            af[mi] = *(const short8*)&Alds[(wm + mi * 16 + lr) * LDA + quad * 8];
        #pragma unroll
        for (int ni = 0; ni < 4; ++ni)
            bf[ni] = *(const short8*)&BldsL[(wn + ni * 16 + lr) * LDB + quad * 8];
        #pragma unroll
        for (int mi = 0; mi < 4; ++mi)
            #pragma unroll
            for (int ni = 0; ni < 4; ++ni)
                acc[mi][ni] = __builtin_amdgcn_mfma_f32_16x16x32_bf16(
                    af[mi], bf[ni], acc[mi][ni], 0, 0, 0);
        __syncthreads();
    }
    #pragma unroll
    for (int ni = 0; ni < 4; ++ni) {
        const int ngl = nt * BN + wn + ni * 16 + lr;
        const float bv = bias[ngl];
        float* ybase = y + (((long)(batch * 512 + ngl)) << 10) + s0;
        #pragma unroll
        for (int mi = 0; mi < 4; ++mi) {
            const int mbase = wm + mi * 16 + quad * 4;
            #pragma unroll
            for (int r = 0; r < 4; ++r)
                ybase[mbase + r] = acc[mi][ni][r] + bv;
        }
    }
}

extern "C" void kernel_launch(void* const* d_in, const int* in_sizes, int n_in,
                              void* d_out, int out_size, void* d_ws, size_t ws_size,
                              hipStream_t stream) {
    const float* x    = (const float*)d_in[0];
    const float* W    = (const float*)d_in[1];
    const float* bias = (const float*)d_in[2];
    float* y          = (float*)d_out;

    const size_t W_ELEMS = 512L * 4096;                       // 2,097,152
    const size_t XPAD_P  = 128L * 256 * 1232;                 // padded stride
    const size_t XPAD_S  = 128L * 256 * 1225;                 // tight stride
    const size_t NEED_P  = (XPAD_P + W_ELEMS) * 2;            // ~84.9 MB
    const size_t NEED_S  = (XPAD_S + W_ELEMS) * 2;            // ~84.5 MB

    if (ws_size >= NEED_P) {
        unsigned short* xpad = (unsigned short*)d_ws;
        unsigned short* Wb   = xpad + XPAD_P;
        hipLaunchKernelGGL(build_pad_vec2, dim3(19712), dim3(256), 0, stream, x, xpad);
        hipLaunchKernelGGL(cvt_w, dim3(1024), dim3(256), 0, stream, W, Wb);
        hipLaunchKernelGGL(convpbc_mfma4, dim3(4096), dim3(256), 0, stream,
                           xpad, Wb, bias, y, 1232);
    } else if (ws_size >= NEED_S) {
        unsigned short* xpad = (unsigned short*)d_ws;
        unsigned short* Wb   = xpad + XPAD_S;
        hipLaunchKernelGGL(build_pad_s, dim3(5, 128 * 256), dim3(256), 0, stream, x, xpad);
        hipLaunchKernelGGL(cvt_w, dim3(1024), dim3(256), 0, stream, W, Wb);
        hipLaunchKernelGGL(convpbc_mfma4, dim3(4096), dim3(256), 0, stream,
                           xpad, Wb, bias, y, 1225);
    } else {
        hipLaunchKernelGGL(convpbc_mfma, dim3(4096), dim3(256), 0, stream, x, W, bias, y);
    }
}

// Round 3
// 1437.392 us; speedup vs baseline: 1.2089x; 1.2089x over previous
//
#include <hip/hip_runtime.h>

// convPbc as implicit GEMM, round 5: counted-vmcnt pipeline at R1's register footprint.
//   - 2 A register sets (af0/af1, 32 VGPR) — A prefetched 1 step ahead; the COMPILER
//     inserts its exact counted vmcnt before the consuming MFMAs (it tracks the
//     global_load_lds builtins in its scoreboard), so A needs no manual wait.
//   - 4 B LDS buffers (32 KB), B-DMA issued 3 steps ahead.
//   - Phase order [A(i+1) then B(i+3)] makes the pre-barrier state exactly
//     [B(i+1)2, A(i)8, B(i+2)2] = 12 outstanding -> manual s_waitcnt vmcnt(12)
//     retires precisely B(i) (the tile about to be read) and keeps 12 ops in
//     flight ACROSS the barrier. Never vmcnt(0) until the tail.
//   - No __launch_bounds__ occupancy cap, no XCD swizzle (R2: 4 resident B-panels
//     = 4MB ~ entire XCD L2 -> thrash), setprio(1) around the MFMA cluster.

#define BM 128
#define BN 128

typedef __attribute__((ext_vector_type(8))) short short8;
typedef __attribute__((ext_vector_type(4))) float f32x4;

struct __attribute__((packed)) u16x4 { unsigned short a, b, c, d; };  // 8B, 2B-align

__device__ __forceinline__ unsigned short f2bf(float f) {
    union { float f; unsigned u; } v; v.f = f;
    unsigned r = v.u + 0x7FFF + ((v.u >> 16) & 1);  // RNE
    return (unsigned short)(r >> 16);
}

__device__ __forceinline__ void async_b128(const void* g, void* l) {
    __builtin_amdgcn_global_load_lds(
        (const __attribute__((address_space(1))) void*)g,
        (__attribute__((address_space(3))) void*)l, 16, 0, 0);
}

// ---------------- pre-pass kernels ----------------
__global__ __launch_bounds__(256) void build_pad_vec2(const float* __restrict__ x,
                                                      unsigned short* __restrict__ xp) {
    const int idx = blockIdx.x * 256 + threadIdx.x;   // 0 .. 32768*154-1
    const int bc  = idx / 154;
    const int t   = idx - bc * 154;
    if (bc >= 32768) return;
    const float* xb = x + (long)bc * 1024;
    union { unsigned short h[8]; short8 v; } u;
    if (t < 128) {                                    // pure copy region v<1024
        const float4 f0 = *(const float4*)(xb + t * 8);
        const float4 f1 = *(const float4*)(xb + t * 8 + 4);
        u.h[0] = f2bf(f0.x); u.h[1] = f2bf(f0.y); u.h[2] = f2bf(f0.z); u.h[3] = f2bf(f0.w);
        u.h[4] = f2bf(f1.x); u.h[5] = f2bf(f1.y); u.h[6] = f2bf(f1.z); u.h[7] = f2bf(f1.w);
    } else {                                          // pad region 1024..1231
        #pragma unroll
        for (int e = 0; e < 8; ++e) {
            const int v = t * 8 + e;
            const int p = (v * 7490) >> 18;           // exact v/35 for v<43690
            const int q = v - p * 35;
            float val = 0.0f;
            if (p >= 32 && q >= 32) val = xb[((p - 32) << 5) + (q - 32)];
            u.h[e] = f2bf(val);
        }
    }
    *(short8*)(xp + (long)bc * 1232 + t * 8) = u.v;
}

// scalar fallback (stride 1225)
__global__ __launch_bounds__(256) void build_pad_s(const float* __restrict__ x,
                                                   unsigned short* __restrict__ xp) {
    const int v = blockIdx.x * 256 + threadIdx.x;
    const int bc = blockIdx.y;
    if (v >= 1225) return;
    const int p = (v * 7490) >> 18;
    const int q = v - p * 35;
    const float* xb = x + (long)bc * 1024;
    float val = (v < 1024) ? xb[v] : 0.0f;
    if (p >= 32 && q >= 32) val += xb[((p - 32) << 5) + (q - 32)];
    xp[(long)bc * 1225 + v] = f2bf(val);
}

__global__ __launch_bounds__(256) void cvt_w(const float* __restrict__ W,
                                             unsigned short* __restrict__ Wb) {
    const int i = (blockIdx.x * 256 + threadIdx.x) * 8;   // 2M elems / 8
    const float4 f0 = *(const float4*)(W + i);
    const float4 f1 = *(const float4*)(W + i + 4);
    union { unsigned short h[8]; short8 v; } u;
    u.h[0] = f2bf(f0.x); u.h[1] = f2bf(f0.y); u.h[2] = f2bf(f0.z); u.h[3] = f2bf(f0.w);
    u.h[4] = f2bf(f1.x); u.h[5] = f2bf(f1.y); u.h[6] = f2bf(f1.z); u.h[7] = f2bf(f1.w);
    *(short8*)(Wb + i) = u.v;
}

// ---------------- main kernel ----------------
__global__ __launch_bounds__(256) void convpbc_mfma5(
    const unsigned short* __restrict__ xpad,  // (128,256,cstride) bf16
    const unsigned short* __restrict__ Wb,    // (512,4096) bf16
    const float* __restrict__ bias,
    float* __restrict__ y,
    const int cstride)
{
    __shared__ __attribute__((aligned(16))) unsigned short Blds[4 * 4096];  // 32 KB

    const int tid = threadIdx.x;
    const int bid = blockIdx.x;            // natural order (no XCD swizzle)
    const int nt = bid & 3;
    const int mt = bid >> 2;
    const int batch = mt >> 3;
    const int s0 = (mt & 7) * BM;
    const int i0 = (mt & 7) * 4;

    const int lane = tid & 63;
    const int w    = tid >> 6;
    const int wm   = (w >> 1) * 64;
    const int wn   = (w & 1) * 64;
    const int lr   = lane & 15;
    const int quad = lane >> 4;

    // ---- A direct-load setup (helical pad: each frag = 2 runs of 4 consecutive) ----
    const int fi0 = (quad & 1) * 2;
    const unsigned short* ab = xpad + (long)(batch * 256 + (quad >> 1)) * cstride;
    int aoff[4];
    #pragma unroll
    for (int mi = 0; mi < 4; ++mi) {
        const int i_mi = i0 + (wm >> 5) + (mi >> 1) + fi0;
        const int j_mi = (mi & 1) * 16 + lr;
        aoff[mi] = i_mi * 35 + j_mi;
    }
    const int csStep = 2 * cstride;   // one k-step = 2 channels

    // ---- B staging setup (global_load_lds, XOR-swizzled k-segments) ----
    const int brow0 = w * 32 + (lane >> 2);
    const int brow1 = brow0 + 16;
    const int bseg  = lane & 3;
    const unsigned short* bg0 =
        Wb + (long)(nt * BN + brow0) * 4096 + (bseg ^ ((brow0 >> 1) & 3)) * 8;
    const unsigned short* bg1 =
        Wb + (long)(nt * BN + brow1) * 4096 + (bseg ^ ((brow1 >> 1) & 3)) * 8;
    unsigned short* const blA = &Blds[(w * 32) * 32];        // wave-uniform DMA bases
    unsigned short* const blB = blA + 512;

    int bfaddr[4];
    #pragma unroll
    for (int ni = 0; ni < 4; ++ni) {
        const int row = wn + ni * 16 + lr;
        bfaddr[ni] = row * 32 + (quad ^ ((row >> 1) & 3)) * 8;
    }

    f32x4 acc[4][4] = {};
    short8 af0[4], af1[4];

    const unsigned short* bg0i = bg0;
    const unsigned short* bg1i = bg1;
    const unsigned short* abi  = ab;

    #define ISSUE_B(BUF, OFF)                                                  \
        async_b128(bg0i + (OFF) * 32, blA + (BUF) * 4096);                     \
        async_b128(bg1i + (OFF) * 32, blB + (BUF) * 4096);
    #define ISSUE_A(SET, OFF)                                                  \
        {                                                                      \
            const unsigned short* ap_ = abi + (OFF) * csStep;                  \
            _Pragma("unroll")                                                  \
            for (int mi = 0; mi < 4; ++mi) {                                   \
                union { unsigned short h[8]; short8 f; } u_;                   \
                *(u16x4*)&u_.h[0] = *(const u16x4*)(ap_ + aoff[mi]);           \
                *(u16x4*)&u_.h[4] = *(const u16x4*)(ap_ + aoff[mi] + 35);      \
                SET[mi] = u_.f;                                                \
            }                                                                  \
        }
    // counted wait for THIS step's B tile only, then barrier. 12 newest ops
    // (B(i+1), A(i), B(i+2)) stay in flight across the barrier.
    #define PHASE_WAIT(N)                                                      \
        asm volatile("s_waitcnt vmcnt(" #N ")" ::: "memory");                  \
        __builtin_amdgcn_s_barrier();                                          \
        __builtin_amdgcn_sched_barrier(0);
    #define COMPUTE_STEP(SET, BUF)                                             \
        {                                                                      \
            short8 bf[4];                                                      \
            _Pragma("unroll")                                                  \
            for (int ni = 0; ni < 4; ++ni)                                     \
                bf[ni] = *(const short8*)&Blds[(BUF) * 4096 + bfaddr[ni]];     \
            __builtin_amdgcn_s_setprio(1);                                     \
            _Pragma("unroll")                                                  \
            for (int mi = 0; mi < 4; ++mi)                                     \
                _Pragma("unroll")                                              \
                for (int ni = 0; ni < 4; ++ni)                                 \
                    acc[mi][ni] = __builtin_amdgcn_mfma_f32_16x16x32_bf16(     \
                        SET[mi], bf[ni], acc[mi][ni], 0, 0, 0);                \
            __builtin_amdgcn_s_setprio(0);                                     \
        }

    // prologue: B(0..2), A(0) -> 14 outstanding entering phase 0
    ISSUE_B(0, 0)
    ISSUE_B(1, 1)
    ISSUE_B(2, 2)
    ISSUE_A(af0, 0)

    // steady loop: 31 iters x 4 phases = steps 0..123
    // phase i: vmcnt(12) retires exactly B(i); issue A(i+1), B(i+3); compute i.
    for (int kb = 0; kb < 31; ++kb) {
        PHASE_WAIT(12) ISSUE_A(af1, 1) ISSUE_B(3, 3) COMPUTE_STEP(af0, 0)
        PHASE_WAIT(12) ISSUE_A(af0, 2) ISSUE_B(0, 4) COMPUTE_STEP(af1, 1)
        PHASE_WAIT(12) ISSUE_A(af1, 3) ISSUE_B(1, 5) COMPUTE_STEP(af0, 2)
        PHASE_WAIT(12) ISSUE_A(af0, 4) ISSUE_B(2, 6) COMPUTE_STEP(af1, 3)
        bg0i += 128; bg1i += 128; abi += 4 * csStep;
    }
    // tail: steps 124..127 (abi/bg at step-124 base)
    PHASE_WAIT(12) ISSUE_A(af1, 1) ISSUE_B(3, 3) COMPUTE_STEP(af0, 0)   // 124
    PHASE_WAIT(12) ISSUE_A(af0, 2)               COMPUTE_STEP(af1, 1)   // 125
    PHASE_WAIT(10) ISSUE_A(af1, 3)               COMPUTE_STEP(af0, 2)   // 126
    PHASE_WAIT(8)                                COMPUTE_STEP(af1, 3)   // 127

    #undef ISSUE_B
    #undef ISSUE_A
    #undef PHASE_WAIT
    #undef COMPUTE_STEP

    // ---- epilogue: C/D layout col=lane&15, row=quad*4+r ----
    #pragma unroll
    for (int ni = 0; ni < 4; ++ni) {
        const int ngl = nt * BN + wn + ni * 16 + lr;
        const float bv = bias[ngl];
        float* ybase = y + (((long)(batch * 512 + ngl)) << 10) + s0;
        #pragma unroll
        for (int mi = 0; mi < 4; ++mi) {
            const int mbase = wm + mi * 16 + quad * 4;
            #pragma unroll
            for (int r = 0; r < 4; ++r)
                ybase[mbase + r] = acc[mi][ni][r] + bv;
        }
    }
}

// ---------------- legacy fallback (fp32 direct, ws too small) ----------------
#define LDA 40
#define LDB 40
__global__ __launch_bounds__(256) void convpbc_mfma(
    const float* __restrict__ x, const float* __restrict__ W,
    const float* __restrict__ bias, float* __restrict__ y)
{
    __shared__ __attribute__((aligned(16))) unsigned short Alds[BM * LDA];
    __shared__ __attribute__((aligned(16))) unsigned short BldsL[BN * LDB];
    const int tid = threadIdx.x, bid = blockIdx.x;
    const int nt = bid & 3, mt = bid >> 2, batch = mt >> 3;
    const int s0 = (mt & 7) * BM;
    const int lane = tid & 63, w = tid >> 6;
    const int wm = (w >> 1) * 64, wn = (w & 1) * 64;
    const int lr = lane & 15, quad = lane >> 4;
    const int sm = tid >> 1, half = tid & 1;
    const int s = s0 + sm, i0 = s >> 5, j0 = s & 31;
    const float* wrow = W + (long)(nt * BN + sm) * 4096;
    f32x4 acc[4][4] = {};
    for (int k0 = 0; k0 < 4096; k0 += 32) {
        {
            const int c = (k0 >> 4) + half;
            const float* xp = x + (((long)(batch * 256 + c)) << 10);
            __attribute__((aligned(16))) unsigned short tmp[16];
            #pragma unroll
            for (int t = 0; t < 16; ++t) {
                const int p = i0 + (t >> 2), q = j0 + (t & 3);
                const int v = p * 35 + q;
                const bool corner = (p >= 32) & (q >= 32);
                const bool valid = corner | (v < 1024);
                int idx = corner ? (((p - 32) << 5) + (q - 32)) : v;
                idx = valid ? idx : 0;
                float fv = xp[idx];
                fv = valid ? fv : 0.0f;
                tmp[t] = f2bf(fv);
            }
            short8* dst = (short8*)&Alds[sm * LDA + half * 16];
            dst[0] = *(const short8*)&tmp[0];
            dst[1] = *(const short8*)&tmp[8];
        }
        {
            const float4* wv = (const float4*)(wrow + k0 + half * 16);
            __attribute__((aligned(16))) unsigned short tmp[16];
            #pragma unroll
            for (int t4 = 0; t4 < 4; ++t4) {
                const float4 f = wv[t4];
                tmp[t4 * 4 + 0] = f2bf(f.x); tmp[t4 * 4 + 1] = f2bf(f.y);
                tmp[t4 * 4 + 2] = f2bf(f.z); tmp[t4 * 4 + 3] = f2bf(f.w);
            }
            short8* dst = (short8*)&BldsL[sm * LDB + half * 16];
            dst[0] = *(const short8*)&tmp[0];
            dst[1] = *(const short8*)&tmp[8];
        }
        __syncthreads();
        short8 af[4], bf[4];
        #pragma unroll
        for (int mi = 0; mi < 4; ++mi)
            af[mi] = *(const short8*)&Alds[(wm + mi * 16 + lr) * LDA + quad * 8];
        #pragma unroll
        for (int ni = 0; ni < 4; ++ni)
            bf[ni] = *(const short8*)&BldsL[(wn + ni * 16 + lr) * LDB + quad * 8];
        #pragma unroll
        for (int mi = 0; mi < 4; ++mi)
            #pragma unroll
            for (int ni = 0; ni < 4; ++ni)
                acc[mi][ni] = __builtin_amdgcn_mfma_f32_16x16x32_bf16(
                    af[mi], bf[ni], acc[mi][ni], 0, 0, 0);
        __syncthreads();
    }
    #pragma unroll
    for (int ni = 0; ni < 4; ++ni) {
        const int ngl = nt * BN + wn + ni * 16 + lr;
        const float bv = bias[ngl];
        float* ybase = y + (((long)(batch * 512 + ngl)) << 10) + s0;
        #pragma unroll
        for (int mi = 0; mi < 4; ++mi) {
            const int mbase = wm + mi * 16 + quad * 4;
            #pragma unroll
            for (int r = 0; r < 4; ++r)
                ybase[mbase + r] = acc[mi][ni][r] + bv;
        }
    }
}

extern "C" void kernel_launch(void* const* d_in, const int* in_sizes, int n_in,
                              void* d_out, int out_size, void* d_ws, size_t ws_size,
                              hipStream_t stream) {
    const float* x    = (const float*)d_in[0];
    const float* W    = (const float*)d_in[1];
    const float* bias = (const float*)d_in[2];
    float* y          = (float*)d_out;

    const size_t W_ELEMS = 512L * 4096;                       // 2,097,152
    const size_t XPAD_P  = 128L * 256 * 1232;                 // padded stride
    const size_t XPAD_S  = 128L * 256 * 1225;                 // tight stride
    const size_t NEED_P  = (XPAD_P + W_ELEMS) * 2;            // ~84.9 MB
    const size_t NEED_S  = (XPAD_S + W_ELEMS) * 2;            // ~84.5 MB

    if (ws_size >= NEED_P) {
        unsigned short* xpad = (unsigned short*)d_ws;
        unsigned short* Wb   = xpad + XPAD_P;
        hipLaunchKernelGGL(build_pad_vec2, dim3(19712), dim3(256), 0, stream, x, xpad);
        hipLaunchKernelGGL(cvt_w, dim3(1024), dim3(256), 0, stream, W, Wb);
        hipLaunchKernelGGL(convpbc_mfma5, dim3(4096), dim3(256), 0, stream,
                           xpad, Wb, bias, y, 1232);
    } else if (ws_size >= NEED_S) {
        unsigned short* xpad = (unsigned short*)d_ws;
        unsigned short* Wb   = xpad + XPAD_S;
        hipLaunchKernelGGL(build_pad_s, dim3(5, 128 * 256), dim3(256), 0, stream, x, xpad);
        hipLaunchKernelGGL(cvt_w, dim3(1024), dim3(256), 0, stream, W, Wb);
        hipLaunchKernelGGL(convpbc_mfma5, dim3(4096), dim3(256), 0, stream,
                           xpad, Wb, bias, y, 1225);
    } else {
        hipLaunchKernelGGL(convpbc_mfma, dim3(4096), dim3(256), 0, stream, x, W, bias, y);
    }
}

// Round 4
// 1128.878 us; speedup vs baseline: 1.5393x; 1.2733x over previous
//
#include <hip/hip_runtime.h>

// convPbc as implicit GEMM, round 6: A moved off the global->register->MFMA chain.
//   R1/R3 post-mortem: 8 per-lane A-gather loads per step force a compiler vmcnt
//   wait right before the MFMA cluster with only 1 phase of cover (deeper needs
//   more af sets -> R2 spilled). Fix: stage A into frag-layout LDS (8KB/step for
//   the whole block, no duplication): per thread 4x8B global loads -> regs
//   (phase i for step i+1) -> 2x ds_write_b128 (late phase i) -> ds_read_b128
//   frags (phase i+1). Per-wave VMEM 10 -> 6 ops/step. B unchanged:
//   global_load_lds double-buffer, counted vmcnt(4) before each barrier.
//   Both A and B frag reads XOR-swizzled (2-way banks = free, m136).

#define BM 128
#define BN 128

typedef __attribute__((ext_vector_type(8))) short short8;
typedef __attribute__((ext_vector_type(4))) float f32x4;

struct __attribute__((packed)) u16x4 { unsigned short a, b, c, d; };  // 8B, 2B-align

__device__ __forceinline__ unsigned short f2bf(float f) {
    union { float f; unsigned u; } v; v.f = f;
    unsigned r = v.u + 0x7FFF + ((v.u >> 16) & 1);  // RNE
    return (unsigned short)(r >> 16);
}

__device__ __forceinline__ void async_b128(const void* g, void* l) {
    __builtin_amdgcn_global_load_lds(
        (const __attribute__((address_space(1))) void*)g,
        (__attribute__((address_space(3))) void*)l, 16, 0, 0);
}

// ---------------- pre-pass kernels ----------------
__global__ __launch_bounds__(256) void build_pad_vec2(const float* __restrict__ x,
                                                      unsigned short* __restrict__ xp) {
    const int idx = blockIdx.x * 256 + threadIdx.x;   // 0 .. 32768*154-1
    const int bc  = idx / 154;
    const int t   = idx - bc * 154;
    if (bc >= 32768) return;
    const float* xb = x + (long)bc * 1024;
    union { unsigned short h[8]; short8 v; } u;
    if (t < 128) {                                    // pure copy region v<1024
        const float4 f0 = *(const float4*)(xb + t * 8);
        const float4 f1 = *(const float4*)(xb + t * 8 + 4);
        u.h[0] = f2bf(f0.x); u.h[1] = f2bf(f0.y); u.h[2] = f2bf(f0.z); u.h[3] = f2bf(f0.w);
        u.h[4] = f2bf(f1.x); u.h[5] = f2bf(f1.y); u.h[6] = f2bf(f1.z); u.h[7] = f2bf(f1.w);
    } else {                                          // pad region 1024..1231
        #pragma unroll
        for (int e = 0; e < 8; ++e) {
            const int v = t * 8 + e;
            const int p = (v * 7490) >> 18;           // exact v/35 for v<43690
            const int q = v - p * 35;
            float val = 0.0f;
            if (p >= 32 && q >= 32) val = xb[((p - 32) << 5) + (q - 32)];
            u.h[e] = f2bf(val);
        }
    }
    *(short8*)(xp + (long)bc * 1232 + t * 8) = u.v;
}

// scalar fallback (stride 1225)
__global__ __launch_bounds__(256) void build_pad_s(const float* __restrict__ x,
                                                   unsigned short* __restrict__ xp) {
    const int v = blockIdx.x * 256 + threadIdx.x;
    const int bc = blockIdx.y;
    if (v >= 1225) return;
    const int p = (v * 7490) >> 18;
    const int q = v - p * 35;
    const float* xb = x + (long)bc * 1024;
    float val = (v < 1024) ? xb[v] : 0.0f;
    if (p >= 32 && q >= 32) val += xb[((p - 32) << 5) + (q - 32)];
    xp[(long)bc * 1225 + v] = f2bf(val);
}

__global__ __launch_bounds__(256) void cvt_w(const float* __restrict__ W,
                                             unsigned short* __restrict__ Wb) {
    const int i = (blockIdx.x * 256 + threadIdx.x) * 8;   // 2M elems / 8
    const float4 f0 = *(const float4*)(W + i);
    const float4 f1 = *(const float4*)(W + i + 4);
    union { unsigned short h[8]; short8 v; } u;
    u.h[0] = f2bf(f0.x); u.h[1] = f2bf(f0.y); u.h[2] = f2bf(f0.z); u.h[3] = f2bf(f0.w);
    u.h[4] = f2bf(f1.x); u.h[5] = f2bf(f1.y); u.h[6] = f2bf(f1.z); u.h[7] = f2bf(f1.w);
    *(short8*)(Wb + i) = u.v;
}

// ---------------- main kernel ----------------
__global__ __launch_bounds__(256) void convpbc_mfma6(
    const unsigned short* __restrict__ xpad,  // (128,256,cstride) bf16
    const unsigned short* __restrict__ Wb,    // (512,4096) bf16
    const float* __restrict__ bias,
    float* __restrict__ y,
    const int cstride)
{
    // [0..8191]   : B slots 0,1 (8KB each)
    // [8192..16383]: A slots 0,1 (8KB each)   (u16 units; 32 KB total)
    __shared__ __attribute__((aligned(16))) unsigned short SH[4 * 4096];

    const int tid = threadIdx.x;
    const int bid = blockIdx.x;
    const int nt = bid & 3;
    const int mt = bid >> 2;
    const int batch = mt >> 3;
    const int s0 = (mt & 7) * BM;

    const int lane = tid & 63;
    const int w    = tid >> 6;
    const int wm   = (w >> 1) * 64;
    const int wn   = (w & 1) * 64;
    const int lr   = lane & 15;
    const int quad = lane >> 4;

    // ---- A staging: thread -> (tile row rw, channel-half h); 4x8B global loads
    //      (fi=0..3 rows of the helical pad) -> 2x ds_write_b128 in frag k-order.
    const int rw = tid >> 1;                 // 0..127
    const int h  = tid & 1;                  // k 0..15 / 16..31 (channel parity)
    const int srow = s0 + rw;
    const int si = srow >> 5, sj = srow & 31;
    const unsigned short* ag = xpad + (long)(batch * 256 + h) * cstride + si * 35 + sj;
    const int xsw = (rw >> 1) & 3;           // k-seg XOR swizzle (matches read side)
    const int aw0off = rw * 32 + (((2 * h) ^ xsw) * 8);
    const int aw1off = rw * 32 + (((2 * h + 1) ^ xsw) * 8);
    const int cs2 = 2 * cstride;             // one k-step = 2 channels

    // ---- A frag read addrs (ds_read_b128, swizzled k-seg) ----
    int afaddr[4];
    #pragma unroll
    for (int mi = 0; mi < 4; ++mi) {
        const int row = wm + mi * 16 + lr;
        afaddr[mi] = 8192 + row * 32 + (quad ^ ((row >> 1) & 3)) * 8;
    }

    // ---- B staging (global_load_lds, XOR-swizzled k-segments) ----
    const int brow0 = w * 32 + (lane >> 2);
    const int brow1 = brow0 + 16;
    const int bseg  = lane & 3;
    const unsigned short* bg0i =
        Wb + (long)(nt * BN + brow0) * 4096 + (bseg ^ ((brow0 >> 1) & 3)) * 8;
    const unsigned short* bg1i =
        Wb + (long)(nt * BN + brow1) * 4096 + (bseg ^ ((brow1 >> 1) & 3)) * 8;
    unsigned short* const blA = &SH[(w * 32) * 32];      // wave-uniform DMA bases
    unsigned short* const blB = blA + 512;

    int bfaddr[4];
    #pragma unroll
    for (int ni = 0; ni < 4; ++ni) {
        const int row = wn + ni * 16 + lr;
        bfaddr[ni] = row * 32 + (quad ^ ((row >> 1) & 3)) * 8;
    }

    f32x4 acc[4][4] = {};
    union areg { u16x4 p[4]; short8 v[2]; };
    areg rsE, rsO;                      // two staging register sets (16 VGPR)
    const unsigned short* agi = ag;

    #define A_LOADS(RS, OFF)                                                   \
        {                                                                      \
            const unsigned short* p_ = agi + (OFF) * cs2;                      \
            RS.p[0] = *(const u16x4*)(p_);                                     \
            RS.p[1] = *(const u16x4*)(p_ + 35);                                \
            RS.p[2] = *(const u16x4*)(p_ + 70);                                \
            RS.p[3] = *(const u16x4*)(p_ + 105);                               \
        }
    #define A_WRITE(RS, SLOT)                                                  \
        *(short8*)&SH[8192 + (SLOT) * 4096 + aw0off] = RS.v[0];                \
        *(short8*)&SH[8192 + (SLOT) * 4096 + aw1off] = RS.v[1];
    #define ISSUE_B(SLOT, OFF)                                                 \
        async_b128(bg0i + (OFF), blA + (SLOT) * 4096);                         \
        async_b128(bg1i + (OFF), blB + (SLOT) * 4096);
    // counted wait: retire this step's B-DMA (oldest 2), keep A(i+1) loads +
    // next B in flight across the barrier. lgkmcnt(0) publishes last phase's
    // A ds_writes before the barrier.
    #define PHASE_SYNC(N)                                                      \
        asm volatile("s_waitcnt vmcnt(" #N ") lgkmcnt(0)" ::: "memory");       \
        __builtin_amdgcn_s_barrier();                                          \
        __builtin_amdgcn_sched_barrier(0);
    #define COMPUTE_STEP(SLOT)                                                 \
        {                                                                      \
            short8 af[4], bf[4];                                               \
            _Pragma("unroll")                                                  \
            for (int ni = 0; ni < 4; ++ni)                                     \
                bf[ni] = *(const short8*)&SH[(SLOT) * 4096 + bfaddr[ni]];      \
            _Pragma("unroll")                                                  \
            for (int mi = 0; mi < 4; ++mi)                                     \
                af[mi] = *(const short8*)&SH[(SLOT) * 4096 + afaddr[mi]];      \
            __builtin_amdgcn_s_setprio(1);                                     \
            _Pragma("unroll")                                                  \
            for (int mi = 0; mi < 4; ++mi)                                     \
                _Pragma("unroll")                                              \
                for (int ni = 0; ni < 4; ++ni)                                 \
                    acc[mi][ni] = __builtin_amdgcn_mfma_f32_16x16x32_bf16(     \
                        af[mi], bf[ni], acc[mi][ni], 0, 0, 0);                 \
            __builtin_amdgcn_s_setprio(0);                                     \
        }

    // ---- prologue: A(0) loaded+written, B(0) in flight, A(1) loads in flight ----
    A_LOADS(rsE, 0)
    A_WRITE(rsE, 0)                        // compiler inserts exact vmcnt wait
    ISSUE_B(0, 0)
    __builtin_amdgcn_sched_barrier(0);     // pin queue order: [B(0), A(1)]
    A_LOADS(rsO, 1)

    // ---- steady loop: steps 0..125 (63 iters x 2) ----
    // phase i: vmcnt(4) retires B(i) [queue: B(i)2,A(i+1)4]; barrier publishes
    // A(i) writes; compute i; issue B(i+1); load A(i+2); write A(i+1).
    for (int kb = 0; kb < 63; ++kb) {
        PHASE_SYNC(4)
        COMPUTE_STEP(0)
        ISSUE_B(1, 32)
        __builtin_amdgcn_sched_barrier(0);
        A_LOADS(rsE, 2)
        A_WRITE(rsO, 1)

        PHASE_SYNC(4)
        COMPUTE_STEP(1)
        ISSUE_B(0, 64)
        __builtin_amdgcn_sched_barrier(0);
        A_LOADS(rsO, 3)
        A_WRITE(rsE, 0)

        agi  += 2 * cs2;
        bg0i += 64;
        bg1i += 64;
    }
    // ---- peel: steps 126, 127 (agi/bg at step-126 base) ----
    PHASE_SYNC(4)                          // retire B(126)
    COMPUTE_STEP(0)
    ISSUE_B(1, 32)                         // B(127)
    A_WRITE(rsO, 1)                        // A(127); compiler vmcnt(2)

    PHASE_SYNC(0)                          // retire B(127)
    COMPUTE_STEP(1)

    #undef A_LOADS
    #undef A_WRITE
    #undef ISSUE_B
    #undef PHASE_SYNC
    #undef COMPUTE_STEP

    // ---- epilogue: C/D layout col=lane&15, row=quad*4+r ----
    #pragma unroll
    for (int ni = 0; ni < 4; ++ni) {
        const int ngl = nt * BN + wn + ni * 16 + lr;
        const float bv = bias[ngl];
        float* ybase = y + (((long)(batch * 512 + ngl)) << 10) + s0;
        #pragma unroll
        for (int mi = 0; mi < 4; ++mi) {
            const int mbase = wm + mi * 16 + quad * 4;
            #pragma unroll
            for (int r = 0; r < 4; ++r)
                ybase[mbase + r] = acc[mi][ni][r] + bv;
        }
    }
}

// ---------------- legacy fallback (fp32 direct, ws too small) ----------------
#define LDA 40
#define LDB 40
__global__ __launch_bounds__(256) void convpbc_mfma(
    const float* __restrict__ x, const float* __restrict__ W,
    const float* __restrict__ bias, float* __restrict__ y)
{
    __shared__ __attribute__((aligned(16))) unsigned short Alds[BM * LDA];
    __shared__ __attribute__((aligned(16))) unsigned short BldsL[BN * LDB];
    const int tid = threadIdx.x, bid = blockIdx.x;
    const int nt = bid & 3, mt = bid >> 2, batch = mt >> 3;
    const int s0 = (mt & 7) * BM;
    const int lane = tid & 63, w = tid >> 6;
    const int wm = (w >> 1) * 64, wn = (w & 1) * 64;
    const int lr = lane & 15, quad = lane >> 4;
    const int sm = tid >> 1, half = tid & 1;
    const int s = s0 + sm, i0 = s >> 5, j0 = s & 31;
    const float* wrow = W + (long)(nt * BN + sm) * 4096;
    f32x4 acc[4][4] = {};
    for (int k0 = 0; k0 < 4096; k0 += 32) {
        {
            const int c = (k0 >> 4) + half;
            const float* xp = x + (((long)(batch * 256 + c)) << 10);
            __attribute__((aligned(16))) unsigned short tmp[16];
            #pragma unroll
            for (int t = 0; t < 16; ++t) {
                const int p = i0 + (t >> 2), q = j0 + (t & 3);
                const int v = p * 35 + q;
                const bool corner = (p >= 32) & (q >= 32);
                const bool valid = corner | (v < 1024);
                int idx = corner ? (((p - 32) << 5) + (q - 32)) : v;
                idx = valid ? idx : 0;
                float fv = xp[idx];
                fv = valid ? fv : 0.0f;
                tmp[t] = f2bf(fv);
            }
            short8* dst = (short8*)&Alds[sm * LDA + half * 16];
            dst[0] = *(const short8*)&tmp[0];
            dst[1] = *(const short8*)&tmp[8];
        }
        {
            const float4* wv = (const float4*)(wrow + k0 + half * 16);
            __attribute__((aligned(16))) unsigned short tmp[16];
            #pragma unroll
            for (int t4 = 0; t4 < 4; ++t4) {
                const float4 f = wv[t4];
                tmp[t4 * 4 + 0] = f2bf(f.x); tmp[t4 * 4 + 1] = f2bf(f.y);
                tmp[t4 * 4 + 2] = f2bf(f.z); tmp[t4 * 4 + 3] = f2bf(f.w);
            }
            short8* dst = (short8*)&BldsL[sm * LDB + half * 16];
            dst[0] = *(const short8*)&tmp[0];
            dst[1] = *(const short8*)&tmp[8];
        }
        __syncthreads();
        short8 af[4], bf[4];
        #pragma unroll
        for (int mi = 0; mi < 4; ++mi)
            af[mi] = *(const short8*)&Alds[(wm + mi * 16 + lr) * LDA + quad * 8];
        #pragma unroll
        for (int ni = 0; ni < 4; ++ni)
            bf[ni] = *(const short8*)&BldsL[(wn + ni * 16 + lr) * LDB + quad * 8];
        #pragma unroll
        for (int mi = 0; mi < 4; ++mi)
            #pragma unroll
            for (int ni = 0; ni < 4; ++ni)
                acc[mi][ni] = __builtin_amdgcn_mfma_f32_16x16x32_bf16(
                    af[mi], bf[ni], acc[mi][ni], 0, 0, 0);
        __syncthreads();
    }
    #pragma unroll
    for (int ni = 0; ni < 4; ++ni) {
        const int ngl = nt * BN + wn + ni * 16 + lr;
        const float bv = bias[ngl];
        float* ybase = y + (((long)(batch * 512 + ngl)) << 10) + s0;
        #pragma unroll
        for (int mi = 0; mi < 4; ++mi) {
            const int mbase = wm + mi * 16 + quad * 4;
            #pragma unroll
            for (int r = 0; r < 4; ++r)
                ybase[mbase + r] = acc[mi][ni][r] + bv;
        }
    }
}

extern "C" void kernel_launch(void* const* d_in, const int* in_sizes, int n_in,
                              void* d_out, int out_size, void* d_ws, size_t ws_size,
                              hipStream_t stream) {
    const float* x    = (const float*)d_in[0];
    const float* W    = (const float*)d_in[1];
    const float* bias = (const float*)d_in[2];
    float* y          = (float*)d_out;

    const size_t W_ELEMS = 512L * 4096;                       // 2,097,152
    const size_t XPAD_P  = 128L * 256 * 1232;                 // padded stride
    const size_t XPAD_S  = 128L * 256 * 1225;                 // tight stride
    const size_t NEED_P  = (XPAD_P + W_ELEMS) * 2;            // ~84.9 MB
    const size_t NEED_S  = (XPAD_S + W_ELEMS) * 2;            // ~84.5 MB

    if (ws_size >= NEED_P) {
        unsigned short* xpad = (unsigned short*)d_ws;
        unsigned short* Wb   = xpad + XPAD_P;
        hipLaunchKernelGGL(build_pad_vec2, dim3(19712), dim3(256), 0, stream, x, xpad);
        hipLaunchKernelGGL(cvt_w, dim3(1024), dim3(256), 0, stream, W, Wb);
        hipLaunchKernelGGL(convpbc_mfma6, dim3(4096), dim3(256), 0, stream,
                           xpad, Wb, bias, y, 1232);
    } else if (ws_size >= NEED_S) {
        unsigned short* xpad = (unsigned short*)d_ws;
        unsigned short* Wb   = xpad + XPAD_S;
        hipLaunchKernelGGL(build_pad_s, dim3(5, 128 * 256), dim3(256), 0, stream, x, xpad);
        hipLaunchKernelGGL(cvt_w, dim3(1024), dim3(256), 0, stream, W, Wb);
        hipLaunchKernelGGL(convpbc_mfma6, dim3(4096), dim3(256), 0, stream,
                           xpad, Wb, bias, y, 1225);
    } else {
        hipLaunchKernelGGL(convpbc_mfma, dim3(4096), dim3(256), 0, stream, x, W, bias, y);
    }
}